// Round 12
// baseline (870.850 us; speedup 1.0000x reference)
//
#include <hip/hip_runtime.h>
#include <hip/hip_bf16.h>

// Problem constants (match reference)
constexpr int B    = 4;
constexpr int N    = 16384;
constexpr int CIN  = 64;
constexpr int COUT = 128;
constexpr int R    = 32;
constexpr int R3   = R * R * R;          // 32768
constexpr int RP   = 34;                 // padded dim
constexpr int RP3  = RP * RP * RP;       // 39304
constexpr int NVOX = B * R3;             // 131072
constexpr float VOX_EPS   = 1e-6f;
constexpr float BN3D_EPS  = 1e-4f;
constexpr float BN1D_EPS  = 1e-5f;
constexpr float LRELU     = 0.1f;

typedef __attribute__((ext_vector_type(8))) short bf16x8;   // 8 bf16 (4 VGPRs)
typedef __attribute__((ext_vector_type(4))) float f32x4;    // MFMA accumulator
typedef __attribute__((ext_vector_type(8))) unsigned short u16x8;

__device__ inline float bf2f(ushort u) {
    union { unsigned int i; float f; } x; x.i = ((unsigned int)u) << 16; return x.f;
}
__device__ inline ushort f2bf(float f) {   // round-to-nearest-even
    union { float f; unsigned int i; } x; x.f = f;
    unsigned int r = x.i + 0x7fffu + ((x.i >> 16) & 1u);
    return (ushort)(r >> 16);
}

// Chunk swizzle folding z bits (R6/R7-proven). Residual ~4 conflict-cycles per
// b128 read are the intrinsic floor — do not chase further.
__device__ inline int swz(int base, int z) {
    return (base ^ (z & 3) ^ ((z >> 2) & 3)) & 3;
}

// Device-scope grid barrier: all blocks of the (co-resident) grid arrive,
// lane 0 spins with acquire semantics. Grid = 256 blocks x 256 thr = 1
// block/CU -> co-residency guaranteed (no deadlock). Counters zeroed by the
// host-side memset each call.
__device__ inline void gridbar(int* bar, int idx, int nblk) {
    __syncthreads();
    if (threadIdx.x == 0) {
        __hip_atomic_fetch_add(&bar[idx], 1, __ATOMIC_ACQ_REL, __HIP_MEMORY_SCOPE_AGENT);
        while (__hip_atomic_load(&bar[idx], __ATOMIC_ACQUIRE, __HIP_MEMORY_SCOPE_AGENT) < nblk) {
            __builtin_amdgcn_s_sleep(1);
        }
    }
    __syncthreads();
}

// nc = clip(((c - mean)/denom + 0.5) * R, 0, R-1)
// stats: per batch 8 floats: [0..2] coord sums, [3] max-norm (f32 bits).
__device__ inline void compute_nc(const float* __restrict__ coords,
                                  const float* __restrict__ stats,
                                  int p, int b, float& nx, float& ny, float& nz) {
    const float invN = 1.0f / (float)N;
    float mmax = __uint_as_float(((const unsigned*)stats)[b * 8 + 3]);
    float denom = mmax * 2.0f + VOX_EPS;
    float cx = coords[(size_t)p * 3 + 0];
    float cy = coords[(size_t)p * 3 + 1];
    float cz = coords[(size_t)p * 3 + 2];
    nx = (cx - stats[b * 8 + 0] * invN) / denom + 0.5f;
    ny = (cy - stats[b * 8 + 1] * invN) / denom + 0.5f;
    nz = (cz - stats[b * 8 + 2] * invN) / denom + 0.5f;
    nx = fminf(fmaxf(nx * (float)R, 0.f), (float)(R - 1));
    ny = fminf(fmaxf(ny * (float)R, 0.f), (float)(R - 1));
    nz = fminf(fmaxf(nz * (float)R, 0.f), (float)(R - 1));
}

// ---------------------------------------------------------------------------
// Mega preprocessing kernel (replaces 9 launches; R11 showed the tail is not
// any one kernel's arithmetic -> attack per-dispatch overhead).
// Grid 256 x 256. Phases separated by device-scope grid barriers:
//  A: zero voxel counts, zero padded borders of gridp+g1p, swizzle weights
//  C: per-batch coord sums (blocks 0..63)        | BAR0
//  D: per-batch max-norm   (blocks 0..63)        | BAR1
//  E: per-point voxel id + slot (1 atomic/point) | BAR2
//  F: per-256-chunk exclusive scan of counts     | BAR3
//  G: scan of 512 chunk totals (block 0)         | BAR4
//  H: scatter point ids into buckets             | BAR5
//  I: wave-per-voxel atomic-free gather-average -> planar bf16 grid
//     (voxels strided v += 1024 to spread the gaussian hot band)
// ---------------------------------------------------------------------------
__global__ __launch_bounds__(256) void k_pre(const float* __restrict__ coords,
                                             const float* __restrict__ feats,
                                             const float* __restrict__ w1,
                                             const float* __restrict__ w2,
                                             const float* __restrict__ pw,
                                             float* __restrict__ stats,
                                             int* __restrict__ bar,
                                             int* __restrict__ cnt,
                                             int* __restrict__ plin,
                                             int* __restrict__ pslot,
                                             int* __restrict__ base,
                                             int* __restrict__ btot,
                                             int* __restrict__ boff,
                                             int* __restrict__ order,
                                             ushort* __restrict__ wq,
                                             ushort* __restrict__ gridp) {
    int tid = threadIdx.x, blk = blockIdx.x;
    int gtid = blk * 256 + tid;            // 0..65535
    __shared__ int s[512];
    __shared__ float red[256];

    // ---- Phase A ----
    cnt[gtid] = 0;
    cnt[gtid + 65536] = 0;
    for (int i = gtid; i < 24 * RP3 * 4; i += 65536) {
        int v = i >> 2;
        int r = v % RP3;
        int z = r % RP;
        int t2 = r / RP;
        int y = t2 % RP;
        int x = (t2 / RP) % RP;
        if (x == 0 || x == RP - 1 || y == 0 || y == RP - 1 || z == 0 || z == RP - 1)
            *(uint4*)(gridp + (size_t)i * 8) = make_uint4(0u, 0u, 0u, 0u);
    }
    for (int idx = gtid; idx < 164 * 4096; idx += 65536) {
        int g = idx >> 12;
        const float* src; int gl;
        if (g < 54)       { src = w1; gl = g; }
        else if (g < 162) { src = w2; gl = g - 54; }
        else              { src = pw; gl = g - 162; }
        int j    = idx & 7;
        int lane = (idx >> 3) & 63;
        int nt   = (idx >> 9) & 7;
        int k = gl * 32 + ((lane >> 4) << 3) + j;
        int n = nt * 16 + (lane & 15);
        wq[idx] = f2bf(src[(size_t)k * COUT + n]);
    }

    // ---- Phase C: coord sums (stats zeroed by host memset) ----
    if (blk < 64) {
        int b = blk >> 4, stripe = blk & 15;
        const float* c = coords + ((size_t)b * N + stripe * 1024) * 3;
        float sx = 0.f, sy = 0.f, sz = 0.f;
        for (int i = tid; i < 1024; i += 256) {
            sx += c[i * 3 + 0];
            sy += c[i * 3 + 1];
            sz += c[i * 3 + 2];
        }
        float vals[3] = {sx, sy, sz};
        for (int k = 0; k < 3; ++k) {
            red[tid] = vals[k];
            __syncthreads();
            for (int st = 128; st > 0; st >>= 1) {
                if (tid < st) red[tid] += red[tid + st];
                __syncthreads();
            }
            if (tid == 0) atomicAdd(&stats[b * 8 + k], red[0]);
            __syncthreads();
        }
    }
    gridbar(bar, 0, 256);

    // ---- Phase D: max-norm ----
    if (blk < 64) {
        int b = blk >> 4, stripe = blk & 15;
        const float invN = 1.0f / (float)N;
        float mx = stats[b * 8 + 0] * invN;
        float my = stats[b * 8 + 1] * invN;
        float mz = stats[b * 8 + 2] * invN;
        const float* c = coords + ((size_t)b * N + stripe * 1024) * 3;
        float mm = 0.f;
        for (int i = tid; i < 1024; i += 256) {
            float dx = c[i * 3 + 0] - mx;
            float dy = c[i * 3 + 1] - my;
            float dz = c[i * 3 + 2] - mz;
            mm = fmaxf(mm, sqrtf(dx * dx + dy * dy + dz * dz));
        }
        red[tid] = mm;
        __syncthreads();
        for (int st = 128; st > 0; st >>= 1) {
            if (tid < st) red[tid] = fmaxf(red[tid], red[tid + st]);
            __syncthreads();
        }
        if (tid == 0)
            atomicMax((unsigned*)&stats[b * 8 + 3], __float_as_uint(red[0]));
    }
    gridbar(bar, 1, 256);

    // ---- Phase E: count (1 int atomic per point) ----
    {
        int p = gtid, b = p >> 14;
        float nx, ny, nz;
        compute_nc(coords, stats, p, b, nx, ny, nz);
        int lin = ((b * R + (int)rintf(nx)) * R + (int)rintf(ny)) * R + (int)rintf(nz);
        plin[p] = lin;
        pslot[p] = atomicAdd(&cnt[lin], 1);
    }
    gridbar(bar, 2, 256);

    // ---- Phase F: per-chunk exclusive scans (2 chunks per block) ----
    for (int cch = blk * 2; cch <= blk * 2 + 1; ++cch) {
        int g = cch * 256 + tid;
        int val = cnt[g];
        s[tid] = val;
        __syncthreads();
        for (int off = 1; off < 256; off <<= 1) {
            int v = tid >= off ? s[tid - off] : 0;
            __syncthreads();
            s[tid] += v;
            __syncthreads();
        }
        base[g] = s[tid] - val;
        if (tid == 255) btot[cch] = s[255];
        __syncthreads();
    }
    gridbar(bar, 3, 256);

    // ---- Phase G: scan 512 chunk totals (block 0 only) ----
    if (blk == 0) {
        int v0 = btot[tid], v1 = btot[tid + 256];
        s[tid] = v0; s[tid + 256] = v1;
        __syncthreads();
        for (int off = 1; off < 256; off <<= 1) {
            int v = tid >= off ? s[tid - off] : 0;
            __syncthreads();
            s[tid] += v;
            __syncthreads();
        }
        int half = s[255];
        __syncthreads();
        for (int off = 1; off < 256; off <<= 1) {
            int v = tid >= off ? s[256 + tid - off] : 0;
            __syncthreads();
            s[256 + tid] += v;
            __syncthreads();
        }
        boff[tid] = s[tid] - v0;
        boff[tid + 256] = s[256 + tid] - v1 + half;
    }
    gridbar(bar, 4, 256);

    // ---- Phase H: fill buckets ----
    {
        int p = gtid;
        int lin = plin[p];
        order[base[lin] + boff[lin >> 8] + pslot[p]] = p;
    }
    gridbar(bar, 5, 256);

    // ---- Phase I: gather-average -> planar padded bf16 grid ----
    {
        int wid = blk * 4 + (tid >> 6);
        int lane = tid & 63;
        for (int v = wid; v < NVOX; v += 1024) {
            int c = cnt[v];
            int bs = base[v] + boff[v >> 8];
            float acc = 0.f;
            for (int j = 0; j < c; ++j) {
                int p = order[bs + j];                 // wave-uniform broadcast
                acc += feats[(size_t)p * CIN + lane];  // coalesced 256B row
            }
            float val = acc / (float)(c == 0 ? 1 : c);
            int vz = v & 31, vy = (v >> 5) & 31, vx = (v >> 10) & 31, b = v >> 15;
            size_t o = ((((size_t)(b * 2 + (lane >> 5)) * RP + vx + 1) * RP + vy + 1) * RP
                        + (vz + 1)) * 32 + (lane & 31);
            gridp[o] = f2bf(val);
        }
    }
}

// ---------------------------------------------------------------------------
// MFMA implicit-GEMM 3x3x3 conv + bias + BN + LeakyReLU.  (R7/R10-verified)
// Input: padded channel-planar [B][CI/32][34][34][34][32] bf16 (borders zero).
// Block = 256 thr (4 waves 2x2): tile M=128 (4 y-columns), N=128.
// Wave (wm,wn) = 64m x 64n. LDS slab [18 rows][34 z][4 ch] XOR-swizzled,
// 39168 B -> 4 blocks/CU.
// REGISTER BUDGET (hard): arch VGPR must stay <= 64. acc[4][4] = 64 AGPRs;
// unified file => 64+64 = 128 = exactly 4 waves/SIMD. R9's hoisted pointer
// array pushed arch to 80 -> 3 waves/SIMD -> regression. R8's LDS pad (49 KB)
// -> 3 blocks/CU -> same regression. Keep inline swz + 39KB.
// __launch_bounds__(256,3): do NOT raise to 4 (R5: spills, 5x regression).
// ---------------------------------------------------------------------------
template <int CI, bool PLANAR_OUT>
__global__ __launch_bounds__(256, 3) void k_conv_mfma(const ushort* __restrict__ in,
                                                      const ushort* __restrict__ wq,
                                                      const float* __restrict__ bias,
                                                      const float* __restrict__ bng,
                                                      const float* __restrict__ bnb,
                                                      const float* __restrict__ bnm,
                                                      const float* __restrict__ bnv,
                                                      ushort* __restrict__ out) {
    constexpr int NCHI = CI / 32;
    __shared__ __align__(16) ushort sl[18 * RP * 32];   // 39168 B

    int bid = blockIdx.x;
    int Y = bid & 7;                  // y-group (4 columns)
    int x = (bid >> 3) & 31;
    int b = bid >> 8;
    int y0 = Y * 4;
    int tid = threadIdx.x;
    int wave = tid >> 6, lane = tid & 63, quad = lane >> 4, l16 = lane & 15;
    int wm = wave >> 1, wn = wave & 1;

    f32x4 acc[4][4] = {};   // [m-tile][n-tile]

    for (int cc = 0; cc < NCHI; ++cc) {
        const ushort* base = in + (((size_t)(b * NCHI + cc) * RP + x) * RP + y0) * RP * 32;
        __syncthreads();
        for (int t = tid; t < 18 * 136; t += 256) {
            int row = t / 136;               // 0..17 = X*6 + Yl
            int r   = t - row * 136;         // 0..135: z = r>>2, ch = r&3
            int X = row / 6, Yl = row - X * 6;
            uint4 v = *(const uint4*)(base + ((size_t)(X * RP + Yl) * RP) * 32 + r * 8);
            int z = r >> 2, ch = r & 3;
            *(uint4*)(sl + ((row * RP + z) * 4 + swz(ch, z)) * 8) = v;
        }
        __syncthreads();

        for (int tap = 0; tap < 27; ++tap) {
            int dx = tap / 9, rem = tap - dx * 9;
            int dy = rem / 3, dz = rem - dy * 3;

            const ushort* bp = wq + ((size_t)((tap * NCHI + cc) * 8 + wn * 4) * 64 + lane) * 8;
            bf16x8 bfr[4], afr[4];
#pragma unroll
            for (int nt = 0; nt < 4; ++nt)
                bfr[nt] = *(const bf16x8*)(bp + nt * 512);
#pragma unroll
            for (int mt = 0; mt < 4; ++mt) {
                int row18 = dx * 6 + wm * 2 + (mt >> 1) + dy;
                int zrow = ((mt & 1) << 4) + l16 + dz;
                afr[mt] = *(const bf16x8*)(sl + ((row18 * RP + zrow) * 4 + swz(quad, zrow)) * 8);
            }
#pragma unroll
            for (int mt = 0; mt < 4; ++mt)
#pragma unroll
                for (int nt = 0; nt < 4; ++nt)
                    acc[mt][nt] = __builtin_amdgcn_mfma_f32_16x16x32_bf16(
                        afr[mt], bfr[nt], acc[mt][nt], 0, 0, 0);
        }
    }

    // Epilogue. C/D layout: col = lane&15 (cout), row = quad*4 + reg (m).
    float sc[4], sb[4], bs[4];
#pragma unroll
    for (int nt = 0; nt < 4; ++nt) {
        int co = wn * 64 + nt * 16 + l16;
        sc[nt] = bng[co] * rsqrtf(bnv[co] + BN3D_EPS);
        sb[nt] = bnb[co] - bnm[co] * sc[nt];
        bs[nt] = bias[co];
    }
#pragma unroll
    for (int mt = 0; mt < 4; ++mt) {
#pragma unroll
        for (int reg = 0; reg < 4; ++reg) {
            int m = wm * 64 + mt * 16 + quad * 4 + reg;
            int i = m >> 5, z = m & 31;
#pragma unroll
            for (int nt = 0; nt < 4; ++nt) {
                float v = (acc[mt][nt][reg] + bs[nt]) * sc[nt] + sb[nt];
                v = v >= 0.f ? v : LRELU * v;
                int co = wn * 64 + nt * 16 + l16;
                if (PLANAR_OUT) {
                    // out planar padded [B][4][34][34][34][32]
                    size_t o = ((((size_t)(b * 4 + (co >> 5)) * RP + (x + 1)) * RP
                                 + (y0 + i + 1)) * RP + (z + 1)) * 32 + (co & 31);
                    out[o] = f2bf(v);
                } else {
                    size_t o = (((size_t)(b * R + x) * R + (y0 + i)) * R + z) * COUT + co;
                    out[o] = f2bf(v);
                }
            }
        }
    }
}

// ---------------------------------------------------------------------------
// Devoxelize + point MLP, two phases. Block = 128 points, 256 thr.
// Phase 1: point MLP via MFMA (pwq read once/block) -> bf16 LDS [128p][128co].
// Phase 2: task = (point, 8-cout chunk): 8 corner rows gathered as bf16x8
// (16B) loads, weighted-summed with the MLP result, stored as coalesced f32.
// Tail: coords passthrough copy folded in (saves a memcpy graph node).
// ---------------------------------------------------------------------------
__global__ __launch_bounds__(256, 2) void k_devox(const float* __restrict__ coords,
                                                  const float* __restrict__ feats,
                                                  const float* __restrict__ stats,
                                                  const ushort* __restrict__ g2,
                                                  const ushort* __restrict__ pwq,
                                                  const float* __restrict__ pb,
                                                  const float* __restrict__ pg,
                                                  const float* __restrict__ pbb,
                                                  const float* __restrict__ pm,
                                                  const float* __restrict__ pv,
                                                  float* __restrict__ out) {
    __shared__ __align__(16) ushort sfeat[128 * 64];   // bf16 A-frags (phase 1)
    __shared__ __align__(16) ushort smlp[128 * 128];   // bf16 MLP result
    __shared__ int   sidx[128 * 8];
    __shared__ float swt[128 * 8];

    int blk = blockIdx.x, tid = threadIdx.x;
    int wave = tid >> 6, lane = tid & 63, quad = lane >> 4, l16 = lane & 15;
    int p0 = blk * 128;

    if (tid < 128) {
        int p = p0 + tid, b = p >> 14;
        float nx, ny, nz;
        compute_nc(coords, stats, p, b, nx, ny, nz);
        int cx0 = (int)floorf(nx), cy0 = (int)floorf(ny), cz0 = (int)floorf(nz);
        float fx = nx - (float)cx0, fy = ny - (float)cy0, fz = nz - (float)cz0;
        int cx1 = min(cx0 + 1, R - 1), cy1 = min(cy0 + 1, R - 1), cz1 = min(cz0 + 1, R - 1);
#pragma unroll
        for (int k = 0; k < 8; ++k) {
            int dx = (k >> 2) & 1, dy = (k >> 1) & 1, dz = k & 1;
            int ix = dx ? cx1 : cx0;
            int iy = dy ? cy1 : cy0;
            int iz = dz ? cz1 : cz0;
            sidx[tid * 8 + k] = (((b * R + ix) * R + iy) * R + iz) * COUT;
            swt[tid * 8 + k] = (dx ? fx : 1.f - fx) * (dy ? fy : 1.f - fy) * (dz ? fz : 1.f - fz);
        }
    }
    // stage feats -> bf16 LDS [128p][64ci], 16B-chunk swizzle phys = ch ^ (p&7)
    for (int i = 0; i < 4; ++i) {
        int c = i * 256 + tid;          // 0..1023
        int p = c >> 3, ch = c & 7;
        const float* src = feats + (size_t)(p0 + p) * CIN + ch * 8;
        float4 f0 = *(const float4*)src;
        float4 f1 = *(const float4*)(src + 4);
        u16x8 u;
        u[0] = f2bf(f0.x); u[1] = f2bf(f0.y); u[2] = f2bf(f0.z); u[3] = f2bf(f0.w);
        u[4] = f2bf(f1.x); u[5] = f2bf(f1.y); u[6] = f2bf(f1.z); u[7] = f2bf(f1.w);
        *(u16x8*)&sfeat[(p * 8 + (ch ^ (p & 7))) * 8] = u;
    }
    __syncthreads();

    // Phase 1: MLP MFMA. pwq groups live at offset 162*4096 in merged wq.
    f32x4 acc[8][2] = {};
#pragma unroll
    for (int cc = 0; cc < 2; ++cc) {
        const ushort* bp = pwq + ((size_t)(cc * 8 + wave * 2) * 64 + lane) * 8;
        bf16x8 b0 = *(const bf16x8*)bp;
        bf16x8 b1 = *(const bf16x8*)(bp + 512);
#pragma unroll
        for (int mt = 0; mt < 8; ++mt) {
            int prow = mt * 16 + l16;
            int ch = cc * 4 + quad;
            bf16x8 a = *(const bf16x8*)&sfeat[(prow * 8 + (ch ^ (prow & 7))) * 8];
            acc[mt][0] = __builtin_amdgcn_mfma_f32_16x16x32_bf16(a, b0, acc[mt][0], 0, 0, 0);
            acc[mt][1] = __builtin_amdgcn_mfma_f32_16x16x32_bf16(a, b1, acc[mt][1], 0, 0, 0);
        }
    }

    int co0 = wave * 32 + l16, co1 = co0 + 16;
    {
        float sc0 = pg[co0] * rsqrtf(pv[co0] + BN1D_EPS);
        float sb0 = pbb[co0] - pm[co0] * sc0;
        float bs0 = pb[co0];
        float sc1 = pg[co1] * rsqrtf(pv[co1] + BN1D_EPS);
        float sb1 = pbb[co1] - pm[co1] * sc1;
        float bs1 = pb[co1];
#pragma unroll
        for (int mt = 0; mt < 8; ++mt) {
#pragma unroll
            for (int reg = 0; reg < 4; ++reg) {
                int pl = mt * 16 + quad * 4 + reg;
                smlp[pl * 128 + co0] = f2bf(fmaxf((acc[mt][0][reg] + bs0) * sc0 + sb0, 0.f));
                smlp[pl * 128 + co1] = f2bf(fmaxf((acc[mt][1][reg] + bs1) * sc1 + sb1, 0.f));
            }
        }
    }
    __syncthreads();

    // Phase 2: vectorized gather + blend. task = (point p, chunk c of 8 couts)
#pragma unroll
    for (int it = 0; it < 8; ++it) {
        int t = it * 256 + tid;          // 0..2047
        int p = t >> 4, c = t & 15;
        float a[8];
        const ushort* m = &smlp[p * 128 + c * 8];
#pragma unroll
        for (int j = 0; j < 8; ++j) a[j] = bf2f(m[j]);
#pragma unroll
        for (int k = 0; k < 8; ++k) {
            int idx = sidx[p * 8 + k];
            float w = swt[p * 8 + k];
            bf16x8 row = *(const bf16x8*)(g2 + (size_t)idx + c * 8);
#pragma unroll
            for (int j = 0; j < 8; ++j) a[j] += w * bf2f(((u16x8)row)[j]);
        }
        float* o = out + (size_t)(p0 + p) * COUT + c * 8;
        *(float4*)o       = make_float4(a[0], a[1], a[2], a[3]);
        *(float4*)(o + 4) = make_float4(a[4], a[5], a[6], a[7]);
    }

    // coords passthrough (output 1), grid-stride
    {
        float* dst = out + (size_t)B * N * COUT;
        for (int i = blk * 256 + tid; i < B * N * 3; i += 512 * 256)
            dst[i] = coords[i];
    }
}

// ---------------------------------------------------------------------------
extern "C" void kernel_launch(void* const* d_in, const int* in_sizes, int n_in,
                              void* d_out, int out_size, void* d_ws, size_t ws_size,
                              hipStream_t stream) {
    const float* feats   = (const float*)d_in[0];
    const float* coords  = (const float*)d_in[1];
    const float* conv1_w = (const float*)d_in[2];
    const float* conv1_b = (const float*)d_in[3];
    const float* bn1_g   = (const float*)d_in[4];
    const float* bn1_b   = (const float*)d_in[5];
    const float* bn1_m   = (const float*)d_in[6];
    const float* bn1_v   = (const float*)d_in[7];
    const float* conv2_w = (const float*)d_in[8];
    const float* conv2_b = (const float*)d_in[9];
    const float* bn2_g   = (const float*)d_in[10];
    const float* bn2_b   = (const float*)d_in[11];
    const float* bn2_m   = (const float*)d_in[12];
    const float* bn2_v   = (const float*)d_in[13];
    const float* pw      = (const float*)d_in[14];
    const float* pb      = (const float*)d_in[15];
    const float* pbn_g   = (const float*)d_in[16];
    const float* pbn_b   = (const float*)d_in[17];
    const float* pbn_m   = (const float*)d_in[18];
    const float* pbn_v   = (const float*)d_in[19];

    // Workspace layout
    char* p = (char*)d_ws;
    float* stats = (float*)p;                        p += 256;
    int*   bar   = (int*)p;                          p += 256;
    int*   cnt   = (int*)p;                          p += (size_t)NVOX * 4;   // zeroed in k_pre
    int*   plin  = (int*)p;                          p += (size_t)B * N * 4;
    int*   pslot = (int*)p;                          p += (size_t)B * N * 4;
    int*   base  = (int*)p;                          p += (size_t)NVOX * 4;
    int*   btot  = (int*)p;                          p += 512 * 4;
    int*   boff  = (int*)p;                          p += 512 * 4;
    int*   order = (int*)p;                          p += (size_t)B * N * 4;
    ushort* gridp = (ushort*)p;                      p += (size_t)B * 2 * RP3 * 32 * 2;
    ushort* g1p   = (ushort*)p;                      p += (size_t)B * 4 * RP3 * 32 * 2;
    ushort* g2b   = (ushort*)p;                      p += (size_t)B * R3 * COUT * 2;
    ushort* wq    = (ushort*)p;                      p += (size_t)164 * 4096 * 2;
    ushort* wq1 = wq;
    ushort* wq2 = wq + 54 * 4096;
    ushort* pwq = wq + 162 * 4096;
    float*  outf  = (float*)d_out;

    // zero stats + grid-barrier counters (512 B, one tiny node)
    hipMemsetAsync(stats, 0, 512, stream);

    // Fused preprocessing (borders+weights+stats+binning+gather): 1 dispatch
    k_pre<<<256, 256, 0, stream>>>(coords, feats, conv1_w, conv2_w, pw,
                                   stats, bar, cnt, plin, pslot, base, btot, boff,
                                   order, wq, gridp);

    k_conv_mfma<CIN, true><<<B * R * (R / 4), 256, 0, stream>>>(
        gridp, wq1, conv1_b, bn1_g, bn1_b, bn1_m, bn1_v, g1p);
    k_conv_mfma<COUT, false><<<B * R * (R / 4), 256, 0, stream>>>(
        g1p, wq2, conv2_b, bn2_g, bn2_b, bn2_m, bn2_v, g2b);

    k_devox<<<(B * N) / 128, 256, 0, stream>>>(coords, feats, stats, g2b, pwq, pb,
                                               pbn_g, pbn_b, pbn_m, pbn_v, outf);
}

// Round 13
// 339.934 us; speedup vs baseline: 2.5618x; 2.5618x over previous
//
#include <hip/hip_runtime.h>
#include <hip/hip_bf16.h>

// Problem constants (match reference)
constexpr int B    = 4;
constexpr int N    = 16384;
constexpr int CIN  = 64;
constexpr int COUT = 128;
constexpr int R    = 32;
constexpr int R3   = R * R * R;          // 32768
constexpr int RP   = 34;                 // padded dim
constexpr int RP3  = RP * RP * RP;       // 39304
constexpr float VOX_EPS   = 1e-6f;
constexpr float BN3D_EPS  = 1e-4f;
constexpr float BN1D_EPS  = 1e-5f;
constexpr float LRELU     = 0.1f;

typedef __attribute__((ext_vector_type(8))) short bf16x8;   // 8 bf16 (4 VGPRs)
typedef __attribute__((ext_vector_type(4))) float f32x4;    // MFMA accumulator
typedef __attribute__((ext_vector_type(8))) unsigned short u16x8;

__device__ inline float bf2f(ushort u) {
    union { unsigned int i; float f; } x; x.i = ((unsigned int)u) << 16; return x.f;
}
__device__ inline ushort f2bf(float f) {   // round-to-nearest-even
    union { float f; unsigned int i; } x; x.f = f;
    unsigned int r = x.i + 0x7fffu + ((x.i >> 16) & 1u);
    return (ushort)(r >> 16);
}

// Chunk swizzle folding z bits (R6/R7-proven). Residual ~4 conflict-cycles per
// b128 read are the intrinsic floor — do not chase further.
// NOTE (R12): do NOT fuse stages with software grid barriers — per-XCD L2
// non-coherence makes spin-release take ~100us per barrier (871us total).
__device__ inline int swz(int base, int z) {
    return (base ^ (z & 3) ^ ((z >> 2) & 3)) & 3;
}

// ---------------------------------------------------------------------------
// stats layout: per batch 8 floats: [0..2] coord sums, [3] max-norm (f32 bits,
// updated via atomicMax on uint — norms >= 0 so order-preserving).
// ---------------------------------------------------------------------------
__global__ __launch_bounds__(256) void k_stats_sum(const float* __restrict__ coords,
                                                   float* __restrict__ stats) {
    int blk = blockIdx.x;            // 64 blocks: b = blk>>4, stripe = blk&15
    int b = blk >> 4, stripe = blk & 15;
    const float* c = coords + ((size_t)b * N + stripe * 1024) * 3;
    float sx = 0.f, sy = 0.f, sz = 0.f;
    for (int i = threadIdx.x; i < 1024; i += 256) {
        sx += c[i * 3 + 0];
        sy += c[i * 3 + 1];
        sz += c[i * 3 + 2];
    }
    __shared__ float red[256];
    float vals[3] = {sx, sy, sz};
    for (int k = 0; k < 3; ++k) {
        red[threadIdx.x] = vals[k];
        __syncthreads();
        for (int s = 128; s > 0; s >>= 1) {
            if (threadIdx.x < s) red[threadIdx.x] += red[threadIdx.x + s];
            __syncthreads();
        }
        if (threadIdx.x == 0) atomicAdd(&stats[b * 8 + k], red[0]);
        __syncthreads();
    }
}

__global__ __launch_bounds__(256) void k_stats_max(const float* __restrict__ coords,
                                                   float* __restrict__ stats) {
    int blk = blockIdx.x;
    int b = blk >> 4, stripe = blk & 15;
    const float invN = 1.0f / (float)N;
    float mx = stats[b * 8 + 0] * invN;
    float my = stats[b * 8 + 1] * invN;
    float mz = stats[b * 8 + 2] * invN;
    const float* c = coords + ((size_t)b * N + stripe * 1024) * 3;
    float mm = 0.f;
    for (int i = threadIdx.x; i < 1024; i += 256) {
        float dx = c[i * 3 + 0] - mx;
        float dy = c[i * 3 + 1] - my;
        float dz = c[i * 3 + 2] - mz;
        mm = fmaxf(mm, sqrtf(dx * dx + dy * dy + dz * dz));
    }
    __shared__ float red[256];
    red[threadIdx.x] = mm;
    __syncthreads();
    for (int s = 128; s > 0; s >>= 1) {
        if (threadIdx.x < s) red[threadIdx.x] = fmaxf(red[threadIdx.x], red[threadIdx.x + s]);
        __syncthreads();
    }
    if (threadIdx.x == 0)
        atomicMax((unsigned*)&stats[b * 8 + 3], __float_as_uint(red[0]));
}

// nc = clip(((c - mean)/denom + 0.5) * R, 0, R-1)
__device__ inline void compute_nc(const float* __restrict__ coords,
                                  const float* __restrict__ stats,
                                  int p, int b, float& nx, float& ny, float& nz) {
    const float invN = 1.0f / (float)N;
    float mmax = __uint_as_float(((const unsigned*)stats)[b * 8 + 3]);
    float denom = mmax * 2.0f + VOX_EPS;
    float cx = coords[(size_t)p * 3 + 0];
    float cy = coords[(size_t)p * 3 + 1];
    float cz = coords[(size_t)p * 3 + 2];
    nx = (cx - stats[b * 8 + 0] * invN) / denom + 0.5f;
    ny = (cy - stats[b * 8 + 1] * invN) / denom + 0.5f;
    nz = (cz - stats[b * 8 + 2] * invN) / denom + 0.5f;
    nx = fminf(fmaxf(nx * (float)R, 0.f), (float)(R - 1));
    ny = fminf(fmaxf(ny * (float)R, 0.f), (float)(R - 1));
    nz = fminf(fmaxf(nz * (float)R, 0.f), (float)(R - 1));
}

// ---------------------------------------------------------------------------
// Scatter-add features into fp32 sums + counts (4 points / block).
// (R11 binning replacement measured neutral — keep the simpler form.)
// ---------------------------------------------------------------------------
__global__ __launch_bounds__(256) void k_scatter(const float* __restrict__ coords,
                                                 const float* __restrict__ feats,
                                                 const float* __restrict__ stats,
                                                 float* __restrict__ sums,
                                                 float* __restrict__ cnt) {
    int sub = threadIdx.x >> 6;        // 0..3
    int ci  = threadIdx.x & 63;
    int p   = blockIdx.x * 4 + sub;    // point index 0..B*N
    __shared__ int s_lin[4];
    if (ci == 0) {
        int b = p >> 14;               // N = 16384
        float nx, ny, nz;
        compute_nc(coords, stats, p, b, nx, ny, nz);
        int vx = (int)rintf(nx);
        int vy = (int)rintf(ny);
        int vz = (int)rintf(nz);
        int lin = ((b * R + vx) * R + vy) * R + vz;
        s_lin[sub] = lin;
        atomicAdd(&cnt[lin], 1.0f);
    }
    __syncthreads();
    atomicAdd(&sums[(size_t)s_lin[sub] * CIN + ci], feats[(size_t)p * CIN + ci]);
}

// ---------------------------------------------------------------------------
// Zero the border voxels of the (contiguous) padded planar buffers.
// buf = [24 planes][34][34][34][32ch] bf16; i enumerates 16B chunks.
// ---------------------------------------------------------------------------
__global__ __launch_bounds__(256) void k_zero_border(ushort* __restrict__ buf, int nchunks) {
    int i = blockIdx.x * 256 + threadIdx.x;
    if (i >= nchunks) return;
    int v = i >> 2;
    int r = v % RP3;
    int z = r % RP;
    int t = r / RP;
    int y = t % RP;
    int x = (t / RP) % RP;
    if (x == 0 || x == RP - 1 || y == 0 || y == RP - 1 || z == 0 || z == RP - 1)
        *(uint4*)(buf + (size_t)i * 8) = make_uint4(0u, 0u, 0u, 0u);
}

// ---------------------------------------------------------------------------
// gridp(bf16, padded planar [B][2][34][34][34][32]) = sums / max(cnt,1)
// ---------------------------------------------------------------------------
__global__ __launch_bounds__(256) void k_finalize(const float* __restrict__ sums,
                                                  const float* __restrict__ cnt,
                                                  ushort* __restrict__ gridp) {
    int i = blockIdx.x * 256 + threadIdx.x;   // B*R3*CIN total
    float c = cnt[i >> 6];
    float val = sums[i] / (c == 0.f ? 1.f : c);
    int ci = i & 63;
    int v = i >> 6;
    int vz = v & 31, vy = (v >> 5) & 31, vx = (v >> 10) & 31, b = v >> 15;
    size_t o = ((((size_t)(b * 2 + (ci >> 5)) * RP + vx + 1) * RP + vy + 1) * RP + vz + 1) * 32
               + (ci & 31);
    gridp[o] = f2bf(val);
}

// ---------------------------------------------------------------------------
// Merged weight swizzle: conv1 (54 groups), conv2 (108), point MLP (2) into
// contiguous wq. wq[((g*8+nt)*64+lane)*8+j] = W[k][n], k = g*32+(lane>>4)*8+j,
// n = nt*16+(lane&15).
// ---------------------------------------------------------------------------
__global__ __launch_bounds__(256) void k_wq_all(const float* __restrict__ w1,
                                                const float* __restrict__ w2,
                                                const float* __restrict__ pw,
                                                ushort* __restrict__ wq) {
    int idx = blockIdx.x * 256 + threadIdx.x;   // < 164*4096
    int g = idx >> 12;
    const float* src; int gl;
    if (g < 54)       { src = w1; gl = g; }
    else if (g < 162) { src = w2; gl = g - 54; }
    else              { src = pw; gl = g - 162; }
    int j    = idx & 7;
    int lane = (idx >> 3) & 63;
    int nt   = (idx >> 9) & 7;
    int k = gl * 32 + ((lane >> 4) << 3) + j;
    int n = nt * 16 + (lane & 15);
    wq[idx] = f2bf(src[(size_t)k * COUT + n]);
}

// ---------------------------------------------------------------------------
// MFMA implicit-GEMM 3x3x3 conv + bias + BN + LeakyReLU.  (R7/R10-verified)
// Input: padded channel-planar [B][CI/32][34][34][34][32] bf16 (borders zero).
// Block = 256 thr (4 waves 2x2): tile M=128 (4 y-columns), N=128.
// Wave (wm,wn) = 64m x 64n. LDS slab [18 rows][34 z][4 ch] XOR-swizzled,
// 39168 B -> 4 blocks/CU.
// REGISTER BUDGET (hard): arch VGPR must stay <= 64. acc[4][4] = 64 AGPRs;
// unified file => 64+64 = 128 = exactly 4 waves/SIMD. R9's hoisted pointer
// array pushed arch to 80 -> 3 waves/SIMD -> regression. R8's LDS pad (49 KB)
// -> 3 blocks/CU -> same regression. Keep inline swz + 39KB.
// __launch_bounds__(256,3): do NOT raise to 4 (R5: spills, 5x regression).
// ---------------------------------------------------------------------------
template <int CI, bool PLANAR_OUT>
__global__ __launch_bounds__(256, 3) void k_conv_mfma(const ushort* __restrict__ in,
                                                      const ushort* __restrict__ wq,
                                                      const float* __restrict__ bias,
                                                      const float* __restrict__ bng,
                                                      const float* __restrict__ bnb,
                                                      const float* __restrict__ bnm,
                                                      const float* __restrict__ bnv,
                                                      ushort* __restrict__ out) {
    constexpr int NCHI = CI / 32;
    __shared__ __align__(16) ushort sl[18 * RP * 32];   // 39168 B

    int bid = blockIdx.x;
    int Y = bid & 7;                  // y-group (4 columns)
    int x = (bid >> 3) & 31;
    int b = bid >> 8;
    int y0 = Y * 4;
    int tid = threadIdx.x;
    int wave = tid >> 6, lane = tid & 63, quad = lane >> 4, l16 = lane & 15;
    int wm = wave >> 1, wn = wave & 1;

    f32x4 acc[4][4] = {};   // [m-tile][n-tile]

    for (int cc = 0; cc < NCHI; ++cc) {
        const ushort* base = in + (((size_t)(b * NCHI + cc) * RP + x) * RP + y0) * RP * 32;
        __syncthreads();
        for (int t = tid; t < 18 * 136; t += 256) {
            int row = t / 136;               // 0..17 = X*6 + Yl
            int r   = t - row * 136;         // 0..135: z = r>>2, ch = r&3
            int X = row / 6, Yl = row - X * 6;
            uint4 v = *(const uint4*)(base + ((size_t)(X * RP + Yl) * RP) * 32 + r * 8);
            int z = r >> 2, ch = r & 3;
            *(uint4*)(sl + ((row * RP + z) * 4 + swz(ch, z)) * 8) = v;
        }
        __syncthreads();

        for (int tap = 0; tap < 27; ++tap) {
            int dx = tap / 9, rem = tap - dx * 9;
            int dy = rem / 3, dz = rem - dy * 3;

            const ushort* bp = wq + ((size_t)((tap * NCHI + cc) * 8 + wn * 4) * 64 + lane) * 8;
            bf16x8 bfr[4], afr[4];
#pragma unroll
            for (int nt = 0; nt < 4; ++nt)
                bfr[nt] = *(const bf16x8*)(bp + nt * 512);
#pragma unroll
            for (int mt = 0; mt < 4; ++mt) {
                int row18 = dx * 6 + wm * 2 + (mt >> 1) + dy;
                int zrow = ((mt & 1) << 4) + l16 + dz;
                afr[mt] = *(const bf16x8*)(sl + ((row18 * RP + zrow) * 4 + swz(quad, zrow)) * 8);
            }
#pragma unroll
            for (int mt = 0; mt < 4; ++mt)
#pragma unroll
                for (int nt = 0; nt < 4; ++nt)
                    acc[mt][nt] = __builtin_amdgcn_mfma_f32_16x16x32_bf16(
                        afr[mt], bfr[nt], acc[mt][nt], 0, 0, 0);
        }
    }

    // Epilogue. C/D layout: col = lane&15 (cout), row = quad*4 + reg (m).
    float sc[4], sb[4], bs[4];
#pragma unroll
    for (int nt = 0; nt < 4; ++nt) {
        int co = wn * 64 + nt * 16 + l16;
        sc[nt] = bng[co] * rsqrtf(bnv[co] + BN3D_EPS);
        sb[nt] = bnb[co] - bnm[co] * sc[nt];
        bs[nt] = bias[co];
    }
#pragma unroll
    for (int mt = 0; mt < 4; ++mt) {
#pragma unroll
        for (int reg = 0; reg < 4; ++reg) {
            int m = wm * 64 + mt * 16 + quad * 4 + reg;
            int i = m >> 5, z = m & 31;
#pragma unroll
            for (int nt = 0; nt < 4; ++nt) {
                float v = (acc[mt][nt][reg] + bs[nt]) * sc[nt] + sb[nt];
                v = v >= 0.f ? v : LRELU * v;
                int co = wn * 64 + nt * 16 + l16;
                if (PLANAR_OUT) {
                    // out planar padded [B][4][34][34][34][32]
                    size_t o = ((((size_t)(b * 4 + (co >> 5)) * RP + (x + 1)) * RP
                                 + (y0 + i + 1)) * RP + (z + 1)) * 32 + (co & 31);
                    out[o] = f2bf(v);
                } else {
                    size_t o = (((size_t)(b * R + x) * R + (y0 + i)) * R + z) * COUT + co;
                    out[o] = f2bf(v);
                }
            }
        }
    }
}

// ---------------------------------------------------------------------------
// Devoxelize + point MLP, two phases. Block = 128 points, 256 thr.
// Phase 1: point MLP via MFMA (pwq read once/block) -> bf16 LDS [128p][128co].
// Phase 2: task = (point, 8-cout chunk): 8 corner rows gathered as bf16x8
// (16B) loads, weighted-summed with the MLP result, stored as coalesced f32.
// Tail: coords passthrough copy folded in (saves the memcpy graph node).
// ---------------------------------------------------------------------------
__global__ __launch_bounds__(256, 2) void k_devox(const float* __restrict__ coords,
                                                  const float* __restrict__ feats,
                                                  const float* __restrict__ stats,
                                                  const ushort* __restrict__ g2,
                                                  const ushort* __restrict__ pwq,
                                                  const float* __restrict__ pb,
                                                  const float* __restrict__ pg,
                                                  const float* __restrict__ pbb,
                                                  const float* __restrict__ pm,
                                                  const float* __restrict__ pv,
                                                  float* __restrict__ out) {
    __shared__ __align__(16) ushort sfeat[128 * 64];   // bf16 A-frags (phase 1)
    __shared__ __align__(16) ushort smlp[128 * 128];   // bf16 MLP result
    __shared__ int   sidx[128 * 8];
    __shared__ float swt[128 * 8];

    int blk = blockIdx.x, tid = threadIdx.x;
    int wave = tid >> 6, lane = tid & 63, quad = lane >> 4, l16 = lane & 15;
    int p0 = blk * 128;

    if (tid < 128) {
        int p = p0 + tid, b = p >> 14;
        float nx, ny, nz;
        compute_nc(coords, stats, p, b, nx, ny, nz);
        int cx0 = (int)floorf(nx), cy0 = (int)floorf(ny), cz0 = (int)floorf(nz);
        float fx = nx - (float)cx0, fy = ny - (float)cy0, fz = nz - (float)cz0;
        int cx1 = min(cx0 + 1, R - 1), cy1 = min(cy0 + 1, R - 1), cz1 = min(cz0 + 1, R - 1);
#pragma unroll
        for (int k = 0; k < 8; ++k) {
            int dx = (k >> 2) & 1, dy = (k >> 1) & 1, dz = k & 1;
            int ix = dx ? cx1 : cx0;
            int iy = dy ? cy1 : cy0;
            int iz = dz ? cz1 : cz0;
            sidx[tid * 8 + k] = (((b * R + ix) * R + iy) * R + iz) * COUT;
            swt[tid * 8 + k] = (dx ? fx : 1.f - fx) * (dy ? fy : 1.f - fy) * (dz ? fz : 1.f - fz);
        }
    }
    // stage feats -> bf16 LDS [128p][64ci], 16B-chunk swizzle phys = ch ^ (p&7)
    for (int i = 0; i < 4; ++i) {
        int c = i * 256 + tid;          // 0..1023
        int p = c >> 3, ch = c & 7;
        const float* src = feats + (size_t)(p0 + p) * CIN + ch * 8;
        float4 f0 = *(const float4*)src;
        float4 f1 = *(const float4*)(src + 4);
        u16x8 u;
        u[0] = f2bf(f0.x); u[1] = f2bf(f0.y); u[2] = f2bf(f0.z); u[3] = f2bf(f0.w);
        u[4] = f2bf(f1.x); u[5] = f2bf(f1.y); u[6] = f2bf(f1.z); u[7] = f2bf(f1.w);
        *(u16x8*)&sfeat[(p * 8 + (ch ^ (p & 7))) * 8] = u;
    }
    __syncthreads();

    // Phase 1: MLP MFMA. pwq groups live at offset 162*4096 in merged wq.
    f32x4 acc[8][2] = {};
#pragma unroll
    for (int cc = 0; cc < 2; ++cc) {
        const ushort* bp = pwq + ((size_t)(cc * 8 + wave * 2) * 64 + lane) * 8;
        bf16x8 b0 = *(const bf16x8*)bp;
        bf16x8 b1 = *(const bf16x8*)(bp + 512);
#pragma unroll
        for (int mt = 0; mt < 8; ++mt) {
            int prow = mt * 16 + l16;
            int ch = cc * 4 + quad;
            bf16x8 a = *(const bf16x8*)&sfeat[(prow * 8 + (ch ^ (prow & 7))) * 8];
            acc[mt][0] = __builtin_amdgcn_mfma_f32_16x16x32_bf16(a, b0, acc[mt][0], 0, 0, 0);
            acc[mt][1] = __builtin_amdgcn_mfma_f32_16x16x32_bf16(a, b1, acc[mt][1], 0, 0, 0);
        }
    }

    int co0 = wave * 32 + l16, co1 = co0 + 16;
    {
        float sc0 = pg[co0] * rsqrtf(pv[co0] + BN1D_EPS);
        float sb0 = pbb[co0] - pm[co0] * sc0;
        float bs0 = pb[co0];
        float sc1 = pg[co1] * rsqrtf(pv[co1] + BN1D_EPS);
        float sb1 = pbb[co1] - pm[co1] * sc1;
        float bs1 = pb[co1];
#pragma unroll
        for (int mt = 0; mt < 8; ++mt) {
#pragma unroll
            for (int reg = 0; reg < 4; ++reg) {
                int pl = mt * 16 + quad * 4 + reg;
                smlp[pl * 128 + co0] = f2bf(fmaxf((acc[mt][0][reg] + bs0) * sc0 + sb0, 0.f));
                smlp[pl * 128 + co1] = f2bf(fmaxf((acc[mt][1][reg] + bs1) * sc1 + sb1, 0.f));
            }
        }
    }
    __syncthreads();

    // Phase 2: vectorized gather + blend. task = (point p, chunk c of 8 couts)
#pragma unroll
    for (int it = 0; it < 8; ++it) {
        int t = it * 256 + tid;          // 0..2047
        int p = t >> 4, c = t & 15;
        float a[8];
        const ushort* m = &smlp[p * 128 + c * 8];
#pragma unroll
        for (int j = 0; j < 8; ++j) a[j] = bf2f(m[j]);
#pragma unroll
        for (int k = 0; k < 8; ++k) {
            int idx = sidx[p * 8 + k];
            float w = swt[p * 8 + k];
            bf16x8 row = *(const bf16x8*)(g2 + (size_t)idx + c * 8);
#pragma unroll
            for (int j = 0; j < 8; ++j) a[j] += w * bf2f(((u16x8)row)[j]);
        }
        float* o = out + (size_t)(p0 + p) * COUT + c * 8;
        *(float4*)o       = make_float4(a[0], a[1], a[2], a[3]);
        *(float4*)(o + 4) = make_float4(a[4], a[5], a[6], a[7]);
    }

    // coords passthrough (output 1), grid-stride over 512 blocks
    {
        float* dst = out + (size_t)B * N * COUT;
        for (int i = blk * 256 + tid; i < B * N * 3; i += 512 * 256)
            dst[i] = coords[i];
    }
}

// ---------------------------------------------------------------------------
extern "C" void kernel_launch(void* const* d_in, const int* in_sizes, int n_in,
                              void* d_out, int out_size, void* d_ws, size_t ws_size,
                              hipStream_t stream) {
    const float* feats   = (const float*)d_in[0];
    const float* coords  = (const float*)d_in[1];
    const float* conv1_w = (const float*)d_in[2];
    const float* conv1_b = (const float*)d_in[3];
    const float* bn1_g   = (const float*)d_in[4];
    const float* bn1_b   = (const float*)d_in[5];
    const float* bn1_m   = (const float*)d_in[6];
    const float* bn1_v   = (const float*)d_in[7];
    const float* conv2_w = (const float*)d_in[8];
    const float* conv2_b = (const float*)d_in[9];
    const float* bn2_g   = (const float*)d_in[10];
    const float* bn2_b   = (const float*)d_in[11];
    const float* bn2_m   = (const float*)d_in[12];
    const float* bn2_v   = (const float*)d_in[13];
    const float* pw      = (const float*)d_in[14];
    const float* pb      = (const float*)d_in[15];
    const float* pbn_g   = (const float*)d_in[16];
    const float* pbn_b   = (const float*)d_in[17];
    const float* pbn_m   = (const float*)d_in[18];
    const float* pbn_v   = (const float*)d_in[19];

    // Workspace layout
    char* p = (char*)d_ws;
    float* stats = (float*)p;                        p += 256;
    float* sums  = (float*)p;                        p += (size_t)B * R3 * CIN * 4;
    float* cnt   = (float*)p;                        p += (size_t)B * R3 * 4;
    ushort* gridp = (ushort*)p;                      p += (size_t)B * 2 * RP3 * 32 * 2;
    ushort* g1p   = (ushort*)p;                      p += (size_t)B * 4 * RP3 * 32 * 2;
    ushort* g2b   = (ushort*)p;                      p += (size_t)B * R3 * COUT * 2;
    ushort* wq    = (ushort*)p;                      p += (size_t)164 * 4096 * 2;
    ushort* wq1 = wq;
    ushort* wq2 = wq + 54 * 4096;
    ushort* pwq = wq + 162 * 4096;
    float*  outf  = (float*)d_out;

    // zero stats + fp32 sums + counts (contiguous)
    hipMemsetAsync(stats, 0, 256 + ((size_t)B * R3 * CIN + (size_t)B * R3) * sizeof(float),
                   stream);
    // zero padded borders of gridp+g1p (contiguous, 24 planes)
    {
        int nc = B * 6 * RP3 * 4;
        k_zero_border<<<(nc + 255) / 256, 256, 0, stream>>>(gridp, nc);
    }

    k_stats_sum<<<64, 256, 0, stream>>>(coords, stats);
    k_stats_max<<<64, 256, 0, stream>>>(coords, stats);
    k_scatter<<<(B * N) / 4, 256, 0, stream>>>(coords, feats, stats, sums, cnt);
    k_finalize<<<(B * R3 * CIN) / 256, 256, 0, stream>>>(sums, cnt, gridp);

    k_wq_all<<<(164 * 4096) / 256, 256, 0, stream>>>(conv1_w, conv2_w, pw, wq);

    k_conv_mfma<CIN, true><<<B * R * (R / 4), 256, 0, stream>>>(
        gridp, wq1, conv1_b, bn1_g, bn1_b, bn1_m, bn1_v, g1p);
    k_conv_mfma<COUT, false><<<B * R * (R / 4), 256, 0, stream>>>(
        g1p, wq2, conv2_b, bn2_g, bn2_b, bn2_m, bn2_v, g2b);

    k_devox<<<(B * N) / 128, 256, 0, stream>>>(coords, feats, stats, g2b, pwq, pb,
                                               pbn_g, pbn_b, pbn_m, pbn_v, outf);
}